// Round 4
// baseline (3858.590 us; speedup 1.0000x reference)
//
#include <hip/hip_runtime.h>
#include <math.h>

#define N_NODES 50000
#define N_EDGES 1000000
#define LAYERS  3
#define G_GRAPHS 512
#define H 128
#define NG 50
#define PI_F 3.14159265358979323846f
#define LOG2_F 0.6931471805599453f

__device__ __forceinline__ float ssp(float v) {
    // softplus(x) - log(2) via hw exp/log; abs err ~1e-6, fine vs threshold
    float t = __expf(-fabsf(v));
    return fmaxf(v, 0.0f) + __logf(1.0f + t) - LOG2_F;
}

// -------------------- h = relu(emb[z]) --------------------
__global__ __launch_bounds__(256) void init_h(const int* __restrict__ z,
                                              const float* __restrict__ emb,
                                              float* __restrict__ h) {
    int idx = blockIdx.x * 256 + threadIdx.x;          // over N*(H/4)
    if (idx >= N_NODES * (H / 4)) return;
    int n = idx >> 5;                                  // H/4 == 32
    int c4 = idx & 31;
    int zv = z[n];
    float4 v = *(const float4*)(emb + (size_t)zv * H + c4 * 4);
    v.x = fmaxf(v.x, 0.f); v.y = fmaxf(v.y, 0.f);
    v.z = fmaxf(v.z, 0.f); v.w = fmaxf(v.w, 0.f);
    *(float4*)(h + (size_t)n * H + c4 * 4) = v;
}

// -------------------- CSR build: sort edges by dst --------------------
__global__ __launch_bounds__(256) void hist_kernel(const int* __restrict__ edst,
                                                   int* __restrict__ cnt) {
    int e = blockIdx.x * 256 + threadIdx.x;
    if (e < N_EDGES) atomicAdd(&cnt[edst[e]], 1);
}

__global__ __launch_bounds__(1024) void scan_kernel(const int* __restrict__ cnt,
                                                    int* __restrict__ cur) {
    __shared__ int buf[1024];
    __shared__ int carry;
    int tid = threadIdx.x;
    if (tid == 0) carry = 0;
    __syncthreads();
    for (int base = 0; base < N_NODES; base += 1024) {
        int i = base + tid;
        int v = (i < N_NODES) ? cnt[i] : 0;
        int incl = v;
        buf[tid] = incl;
        __syncthreads();
        for (int s = 1; s < 1024; s <<= 1) {
            int t = (tid >= s) ? buf[tid - s] : 0;
            __syncthreads();
            incl += t;
            buf[tid] = incl;
            __syncthreads();
        }
        int cbase = carry;
        if (i < N_NODES) cur[i] = cbase + incl - v;
        __syncthreads();
        if (tid == 1023) carry = cbase + incl;
        __syncthreads();
    }
}

__global__ __launch_bounds__(256) void scatter_kernel(const int* __restrict__ edst,
                                                      int* __restrict__ cur,
                                                      int* __restrict__ perm) {
    int e = blockIdx.x * 256 + threadIdx.x;
    if (e < N_EDGES) {
        int p = atomicAdd(&cur[edst[e]], 1);
        perm[p] = e;
    }
}

// -------------------- generic node GEMM (unchanged this round) --------------------
#define F_BIAS 1
#define F_SSPA 2
#define F_ACCUM 4
#define F_POOL 8

template <int FLAGS>
__global__ __launch_bounds__(256, 4) void node_gemm(const float* __restrict__ A,
                                                    const float* __restrict__ B,
                                                    const float* __restrict__ bias,
                                                    float* __restrict__ Out,
                                                    const int* __restrict__ batch,
                                                    int nRows, int NC) {
    __shared__ float Atc[128 * 65];    // A tile transposed: [k][row], ld 65
    int tid = threadIdx.x;
    int rowBase = blockIdx.x * 64;
    int colOff = blockIdx.y * 128;
    int rlim = nRows - rowBase; if (rlim > 64) rlim = 64;

    for (int idx = tid; idx < 64 * 128; idx += 256) {
        int r = idx >> 7, k = idx & 127;
        float v = 0.f;
        if (r < rlim) {
            v = A[(size_t)(rowBase + r) * H + k];
            if (FLAGS & F_SSPA) v = ssp(v);
        }
        Atc[k * 65 + r] = v;
    }
    __syncthreads();

    int cg = tid & 15, rg = tid >> 4;
    int r0 = rg * 4;
    int gc0 = colOff + cg * 4, gc1 = colOff + 64 + cg * 4;

    float acc[4][8];
#pragma unroll
    for (int j = 0; j < 4; ++j) {
        float b0 = 0.f, b1v = 0.f;
        if (FLAGS & F_BIAS) { b0 = bias[gc0 + j]; b1v = bias[gc1 + j]; }
#pragma unroll
        for (int i = 0; i < 4; ++i) { acc[i][j] = b0; acc[i][4 + j] = b1v; }
    }

#pragma unroll 4
    for (int k = 0; k < H; ++k) {
        float4 a4 = *(float4*)(Atc + k * 65 + r0);
        float4 w0 = *(const float4*)(B + (size_t)k * NC + gc0);
        float4 w1 = *(const float4*)(B + (size_t)k * NC + gc1);
        float av[4] = {a4.x, a4.y, a4.z, a4.w};
        float wv[8] = {w0.x, w0.y, w0.z, w0.w, w1.x, w1.y, w1.z, w1.w};
#pragma unroll
        for (int i = 0; i < 4; ++i)
#pragma unroll
            for (int j = 0; j < 8; ++j) acc[i][j] = fmaf(av[i], wv[j], acc[i][j]);
    }

    if (FLAGS & F_POOL) {
        int cur = -1;
        float sA[4] = {0, 0, 0, 0}, sB[4] = {0, 0, 0, 0};
#pragma unroll
        for (int i = 0; i < 4; ++i) {
            int r = r0 + i;
            int b = (r < rlim) ? batch[rowBase + r] : -1;
            if (b != cur) {
                if (cur >= 0) {
#pragma unroll
                    for (int j = 0; j < 4; ++j) {
                        unsafeAtomicAdd(Out + (size_t)cur * NC + gc0 + j, sA[j]);
                        unsafeAtomicAdd(Out + (size_t)cur * NC + gc1 + j, sB[j]);
                    }
                }
                cur = b;
#pragma unroll
                for (int j = 0; j < 4; ++j) { sA[j] = 0.f; sB[j] = 0.f; }
            }
            if (b >= 0) {
#pragma unroll
                for (int j = 0; j < 4; ++j) {
                    sA[j] += ssp(acc[i][j]);
                    sB[j] += ssp(acc[i][4 + j]);
                }
            }
        }
        if (cur >= 0) {
#pragma unroll
            for (int j = 0; j < 4; ++j) {
                unsafeAtomicAdd(Out + (size_t)cur * NC + gc0 + j, sA[j]);
                unsafeAtomicAdd(Out + (size_t)cur * NC + gc1 + j, sB[j]);
            }
        }
    } else {
#pragma unroll
        for (int i = 0; i < 4; ++i) {
            int r = r0 + i;
            if (r >= rlim) break;
            float* orow = Out + (size_t)(rowBase + r) * NC;
            float4 vA = make_float4(acc[i][0], acc[i][1], acc[i][2], acc[i][3]);
            float4 vB = make_float4(acc[i][4], acc[i][5], acc[i][6], acc[i][7]);
            if (FLAGS & F_ACCUM) {
                float4 oA = *(float4*)(orow + gc0);
                float4 oB = *(float4*)(orow + gc1);
                vA.x += oA.x; vA.y += oA.y; vA.z += oA.z; vA.w += oA.w;
                vB.x += oB.x; vB.y += oB.y; vB.z += oB.z; vB.w += oB.w;
            }
            *(float4*)(orow + gc0) = vA;
            *(float4*)(orow + gc1) = vB;
        }
    }
}

// -------------------- fused edge kernel, lane=edge / scalar-W --------------------
// 64 edges per 128-thread block (2 waves = column halves). Weight addresses are
// wave-uniform -> scalar loads (lgkmcnt, scalar pipe) -> no vmcnt in the FMA
// loop. Activations: one conflict-free ds_read_b32 per k-step. GEMM2 runs in
// two k=64 phases through one 17 KB LDS buffer. Epilogue transposes Wf via LDS
// so x-gather and agg stores are coalesced (lane=column), with dst-run
// compaction (sorted edges) and atomics only for window-crossing runs.
__global__ __launch_bounds__(128, 3) void edge_kernel(const float* __restrict__ eattr,
                                                      const float* __restrict__ ew,
                                                      const int* __restrict__ esrc,
                                                      const int* __restrict__ edst,
                                                      const int* __restrict__ perm,
                                                      const float* __restrict__ W1,
                                                      const float* __restrict__ b1,
                                                      const float* __restrict__ W2,
                                                      const float* __restrict__ b2,
                                                      const float* __restrict__ x,
                                                      float* __restrict__ agg) {
    __shared__ float buf[64 * 72];     // attrT[50][68] -> Tt[64][68] -> Wfs[32][132]
    __shared__ int Se[64], De[64], Ge[64];
    __shared__ float Ce[64];
    __shared__ int bnd[2];             // prev-block last dst, next-block first dst

    int tid = threadIdx.x;
    int e0 = blockIdx.x * 64;
    int lane = tid & 63;
    int half = __builtin_amdgcn_readfirstlane(tid >> 6);   // wave-uniform 0/1
    int cbase = half * 64;

    if (tid < 64) {
        int ge = perm[e0 + tid];
        Ge[tid] = ge;
        Se[tid] = esrc[ge];
        De[tid] = edst[ge];
        Ce[tid] = 0.5f * (cosf(ew[ge] * (PI_F / 10.0f)) + 1.0f);
    }
    if (tid == 64) bnd[0] = (e0 > 0) ? edst[perm[e0 - 1]] : -1;
    if (tid == 65) bnd[1] = (e0 + 64 < N_EDGES) ? edst[perm[e0 + 64]] : -1;
    __syncthreads();

    // ---- stage attr transposed [k][e] ----
    float* attrT = buf;
    for (int idx = tid; idx < 64 * NG; idx += 128) {
        int e = idx / NG, k = idx - e * NG;
        attrT[k * 68 + e] = eattr[(size_t)Ge[e] * NG + k];
    }
    __syncthreads();

    // ---- GEMM1: acc[c] = b1[c] + sum_k attr[e][k] * W1[k][cbase+c] ----
    float acc[64];
#pragma unroll
    for (int c = 0; c < 64; ++c) acc[c] = b1[cbase + c];
#pragma unroll 2
    for (int k = 0; k < NG; ++k) {
        float tk = attrT[k * 68 + lane];
        const float* wr = W1 + (size_t)k * H + cbase;      // wave-uniform -> s_load
#pragma unroll
        for (int c4 = 0; c4 < 16; ++c4) {
            float4 w = *(const float4*)(wr + c4 * 4);
            acc[c4 * 4 + 0] = fmaf(tk, w.x, acc[c4 * 4 + 0]);
            acc[c4 * 4 + 1] = fmaf(tk, w.y, acc[c4 * 4 + 1]);
            acc[c4 * 4 + 2] = fmaf(tk, w.z, acc[c4 * 4 + 2]);
            acc[c4 * 4 + 3] = fmaf(tk, w.w, acc[c4 * 4 + 3]);
        }
    }
    __syncthreads();   // attrT dead; Tt overlays

    // ---- GEMM2 phase A: wave0 publishes T cols 0..63; all FMA k=0..63 ----
    float* Tt = buf;
    if (half == 0) {
#pragma unroll
        for (int c = 0; c < 64; ++c) Tt[c * 68 + lane] = ssp(acc[c]);
    }
    __syncthreads();

    float acc2[64];
#pragma unroll
    for (int c = 0; c < 64; ++c) acc2[c] = b2[cbase + c];
#pragma unroll 2
    for (int k = 0; k < 64; ++k) {
        float tk = Tt[k * 68 + lane];
        const float* wr = W2 + (size_t)k * H + cbase;      // wave-uniform -> s_load
#pragma unroll
        for (int c4 = 0; c4 < 16; ++c4) {
            float4 w = *(const float4*)(wr + c4 * 4);
            acc2[c4 * 4 + 0] = fmaf(tk, w.x, acc2[c4 * 4 + 0]);
            acc2[c4 * 4 + 1] = fmaf(tk, w.y, acc2[c4 * 4 + 1]);
            acc2[c4 * 4 + 2] = fmaf(tk, w.z, acc2[c4 * 4 + 2]);
            acc2[c4 * 4 + 3] = fmaf(tk, w.w, acc2[c4 * 4 + 3]);
        }
    }
    __syncthreads();

    // ---- GEMM2 phase B: wave1 publishes T cols 64..127; all FMA k=64..127 ----
    if (half == 1) {
#pragma unroll
        for (int c = 0; c < 64; ++c) Tt[c * 68 + lane] = ssp(acc[c]);
    }
    __syncthreads();
#pragma unroll 2
    for (int k = 0; k < 64; ++k) {
        float tk = Tt[k * 68 + lane];
        const float* wr = W2 + (size_t)(64 + k) * H + cbase;
#pragma unroll
        for (int c4 = 0; c4 < 16; ++c4) {
            float4 w = *(const float4*)(wr + c4 * 4);
            acc2[c4 * 4 + 0] = fmaf(tk, w.x, acc2[c4 * 4 + 0]);
            acc2[c4 * 4 + 1] = fmaf(tk, w.y, acc2[c4 * 4 + 1]);
            acc2[c4 * 4 + 2] = fmaf(tk, w.z, acc2[c4 * 4 + 2]);
            acc2[c4 * 4 + 3] = fmaf(tk, w.w, acc2[c4 * 4 + 3]);
        }
    }

    // ---- epilogue: Wf = acc2 * C; transpose via LDS; coalesced run-compacted scatter ----
    float cf = Ce[lane];
#pragma unroll
    for (int c = 0; c < 64; ++c) acc2[c] *= cf;

    float* Wfs = buf;                  // overlay, [32][132]
    for (int hf = 0; hf < 2; ++hf) {
        __syncthreads();               // Tt reads done (hf=0) / prev window done (hf=1)
        if ((lane >> 5) == hf) {
            int er = lane & 31;
#pragma unroll
            for (int c4 = 0; c4 < 16; ++c4)
                *(float4*)(Wfs + er * 132 + cbase + c4 * 4) =
                    make_float4(acc2[c4 * 4 + 0], acc2[c4 * 4 + 1],
                                acc2[c4 * 4 + 2], acc2[c4 * 4 + 3]);
        }
        __syncthreads();
        // scatter window: 128 lanes = 128 cols; edges ebase..ebase+31 (dst-sorted)
        int c = tid;
        int ebase = hf * 32;
        int wprev = (hf == 0) ? bnd[0] : De[31];
        int wnext = (hf == 0) ? De[32] : bnd[1];
        float rsum = 0.f;
        int rd = De[ebase];
        bool first = true;
#pragma unroll 4
        for (int e = 0; e < 32; ++e) {
            int d = De[ebase + e];
            if (d != rd) {             // wave-uniform branch (De same for all lanes)
                float* p = agg + (size_t)rd * H + c;
                if (first && rd == wprev) unsafeAtomicAdd(p, rsum);
                else *p = rsum;
                first = false;
                rsum = 0.f;
                rd = d;
            }
            rsum = fmaf(Wfs[e * 132 + c], x[(size_t)Se[ebase + e] * H + c], rsum);
        }
        float* p = agg + (size_t)rd * H + c;
        if ((first && rd == wprev) || rd == wnext) unsafeAtomicAdd(p, rsum);
        else *p = rsum;
    }
}

// -------------------- out = ssp(pooled@ro_w2 + b2) @ ro_w3 + b3 --------------------
__global__ __launch_bounds__(128) void final_out(const float* __restrict__ pooled,
                                                 const float* __restrict__ ro_w2,
                                                 const float* __restrict__ ro_b2,
                                                 const float* __restrict__ ro_w3,
                                                 const float* __restrict__ ro_b3,
                                                 float* __restrict__ out) {
    int g = blockIdx.x;
    int c = threadIdx.x;     // 128
    float acc = ro_b2[c];
    const float* pr = pooled + (size_t)g * (5 * H);
    for (int k = 0; k < 5 * H; ++k) acc = fmaf(pr[k], ro_w2[(size_t)k * H + c], acc);
    float v = ssp(acc) * ro_w3[c];
    __shared__ float red[128];
    red[c] = v;
    __syncthreads();
    for (int s = 64; s > 0; s >>= 1) {
        if (c < s) red[c] += red[c + s];
        __syncthreads();
    }
    if (c == 0) out[g] = red[0] + ro_b3[0];
}

extern "C" void kernel_launch(void* const* d_in, const int* in_sizes, int n_in,
                              void* d_out, int out_size, void* d_ws, size_t ws_size,
                              hipStream_t stream) {
    const int* z     = (const int*)d_in[0];
    const int* esrc  = (const int*)d_in[1];
    const int* edst  = (const int*)d_in[2];
    const int* batch = (const int*)d_in[3];
    const float* ew    = (const float*)d_in[5];
    const float* eattr = (const float*)d_in[6];
    const float* emb   = (const float*)d_in[7];
    const float* mlp_w1 = (const float*)d_in[8];
    const float* mlp_b1 = (const float*)d_in[9];
    const float* mlp_w2 = (const float*)d_in[10];
    const float* mlp_b2 = (const float*)d_in[11];
    const float* cf_w1  = (const float*)d_in[12];
    const float* cf_w2  = (const float*)d_in[13];
    const float* cf_b2  = (const float*)d_in[14];
    const float* lin_w  = (const float*)d_in[15];
    const float* lin_b  = (const float*)d_in[16];
    const float* ro_w1  = (const float*)d_in[17];
    const float* ro_b1  = (const float*)d_in[18];
    const float* ro_w2  = (const float*)d_in[19];
    const float* ro_b2  = (const float*)d_in[20];
    const float* ro_w3  = (const float*)d_in[21];
    const float* ro_b3  = (const float*)d_in[22];
    float* out = (float*)d_out;

    float* h      = (float*)d_ws;
    float* x      = h + (size_t)N_NODES * H;
    float* agg    = x + (size_t)N_NODES * H;
    float* pooled = agg + (size_t)N_NODES * H;
    int*   cnt    = (int*)(pooled + (size_t)G_GRAPHS * 5 * H);
    int*   cur    = cnt + N_NODES;
    int*   perm   = cur + N_NODES;

    init_h<<<(N_NODES * (H / 4) + 255) / 256, 256, 0, stream>>>(z, emb, h);

    // CSR build (once; reused by all 3 layers)
    hipMemsetAsync(cnt, 0, N_NODES * sizeof(int), stream);
    hist_kernel<<<(N_EDGES + 255) / 256, 256, 0, stream>>>(edst, cnt);
    scan_kernel<<<1, 1024, 0, stream>>>(cnt, cur);
    scatter_kernel<<<(N_EDGES + 255) / 256, 256, 0, stream>>>(edst, cur, perm);

    int rowTiles = (N_NODES + 63) / 64;  // 782
    for (int l = 0; l < LAYERS; ++l) {
        node_gemm<0><<<dim3(rowTiles, 1), 256, 0, stream>>>(
            h, cf_w1 + (size_t)l * H * H, nullptr, x, nullptr, N_NODES, H);
        hipMemsetAsync(agg, 0, (size_t)N_NODES * H * sizeof(float), stream);
        edge_kernel<<<N_EDGES / 64, 128, 0, stream>>>(
            eattr, ew, esrc, edst, perm,
            mlp_w1 + (size_t)l * NG * H, mlp_b1 + (size_t)l * H,
            mlp_w2 + (size_t)l * H * H, mlp_b2 + (size_t)l * H, x, agg);
        node_gemm<F_BIAS><<<dim3(rowTiles, 1), 256, 0, stream>>>(
            agg, cf_w2 + (size_t)l * H * H, cf_b2 + (size_t)l * H, x, nullptr, N_NODES, H);
        node_gemm<F_BIAS | F_SSPA | F_ACCUM><<<dim3(rowTiles, 1), 256, 0, stream>>>(
            x, lin_w + (size_t)l * H * H, lin_b + (size_t)l * H, h, nullptr, N_NODES, H);
    }

    hipMemsetAsync(pooled, 0, (size_t)G_GRAPHS * 5 * H * sizeof(float), stream);
    node_gemm<F_BIAS | F_POOL><<<dim3(rowTiles, 5), 256, 0, stream>>>(
        h, ro_w1, ro_b1, pooled, batch, N_NODES, 5 * H);
    final_out<<<G_GRAPHS, 128, 0, stream>>>(pooled, ro_w2, ro_b2, ro_w3, ro_b3, out);
}